// Round 1
// baseline (105.291 us; speedup 1.0000x reference)
//
#include <hip/hip_runtime.h>
#include <math.h>

// Problem constants (from reference setup_inputs)
constexpr int Bb = 128;   // batches
constexpr int Nn = 64;    // events per sequence (times0/times1)
constexpr int Hh = 128;   // head events
constexpr int Gg = 4000;  // grid points
constexpr float  TOLf = 0.5f;
constexpr double RESd = 0.03;
constexpr int GB = 16;    // grid blocks per batch: 16*256 = 4096 >= 4000

// Fused kernel:
//   blocks [0, Bb*GB)        : grid-integral points, block -> (b, 256 g's)
//   blocks [Bb*GB, Bb*GB+Bb) : event log-likelihood points, block -> b
__global__ __launch_bounds__(256) void llm_kernel(
    const float* __restrict__ times0, const int* __restrict__ states0,
    const float* __restrict__ times1, const int* __restrict__ states1,
    const float* __restrict__ head_times, const int* __restrict__ head_states,
    const float* __restrict__ base, const float* __restrict__ weights,
    double* __restrict__ acc)
{
    __shared__ float  t0s[Nn], t1s[Nn];
    __shared__ double Wsh[Nn];          // s0==1 ? exp(t0) : 0
    __shared__ double PJsh[Nn];         // P[j0(i)]
    __shared__ double Ps[Nn + 1];       // prefix of (s1==1 ? exp(t1) : 0)
    __shared__ double Qs[Nn + 1];       // prefix of (s0==0 ? exp(t0) : 0)
    __shared__ double tmp0[Nn], tmp1[Nn];
    __shared__ float  hts[Hh];
    __shared__ int    hss[Hh];
    __shared__ double red[256];

    const int tid = threadIdx.x;
    const bool isEvent = blockIdx.x >= (unsigned)(Bb * GB);
    const int b = isEvent ? (blockIdx.x - Bb * GB) : (blockIdx.x / GB);

    // ---- per-batch precompute (tiny; redundant per block, amortized) ----
    if (tid < Nn) {
        t0s[tid] = times0[b * Nn + tid];
        t1s[tid] = times1[b * Nn + tid];
    }
    if (tid < Hh) {
        hts[tid] = head_times[b * Hh + tid];
        hss[tid] = head_states[b * Hh + tid];
    }
    __syncthreads();

    int j0 = 0;
    if (tid < Nn) {
        const float myt0 = t0s[tid];
        int cntj = 0;
        #pragma unroll
        for (int j = 0; j < Nn; ++j)
            cntj += (myt0 - t1s[j] >= -TOLf) ? 1 : 0;   // NOT(M) count, fp32 cmp as in ref
        j0 = cntj;
        const int s0v = states0[b * Nn + tid];
        const int s1v = states1[b * Nn + tid];
        tmp1[tid] = (s1v == 1) ? exp((double)t1s[tid]) : 0.0;
        tmp0[tid] = (s0v == 0) ? exp((double)myt0)     : 0.0;
        Wsh[tid]  = (s0v == 1) ? exp((double)myt0)     : 0.0;
    }
    __syncthreads();
    if (tid == 0) {
        double p = 0.0, q = 0.0;
        Ps[0] = 0.0; Qs[0] = 0.0;
        for (int k = 0; k < Nn; ++k) {
            p += tmp1[k]; Ps[k + 1] = p;
            q += tmp0[k]; Qs[k + 1] = q;
        }
    }
    __syncthreads();
    if (tid < Nn) PJsh[tid] = Ps[j0];
    __syncthreads();

    // softmax(weights), base — cheap per-thread
    const double w0 = (double)weights[0], w1 = (double)weights[1];
    const double mw = fmax(w0, w1);
    const double ew0 = exp(w0 - mw), ew1 = exp(w1 - mw);
    const double wn0 = ew0 / (ew0 + ew1), wn1 = ew1 / (ew0 + ew1);
    const double bse = (double)base[0];

    // ---- point evaluation ----
    double contrib = 0.0;
    float t = 0.0f;
    bool active = false;
    if (isEvent) {
        if (tid >= 1 && tid < Hh) { t = hts[tid]; active = true; }
    } else {
        const int g = (blockIdx.x % GB) * 256 + tid;
        if (g < Gg) { t = (float)g * 0.03f; active = true; }
    }

    if (active) {
        const float thr = t - TOLf;   // fp32, as in reference (te - TOL)

        // c = #{ t1 < thr }  (binary search, sorted ascending)
        int lo = 0, hi = Nn;
        while (lo < hi) { int mid = (lo + hi) >> 1; if (t1s[mid] < thr) lo = mid + 1; else hi = mid; }
        const int c = lo;
        // c0 = #{ t0 < thr }
        lo = 0; hi = Nn;
        while (lo < hi) { int mid = (lo + hi) >> 1; if (t0s[mid] < thr) lo = mid + 1; else hi = mid; }
        const int c0 = lo;
        // cnt = #{ head_times < t }
        lo = 0; hi = Hh;
        while (lo < hi) { int mid = (lo + hi) >> 1; if (hts[mid] < t) lo = mid + 1; else hi = mid; }
        const int cnt = lo;

        const double Pc = Ps[c];
        double a = 0.0;
        #pragma unroll
        for (int i = 0; i < Nn; ++i) {
            const double term = Wsh[i] * fmax(Pc - PJsh[i], 0.0);
            a += (t0s[i] <= t) ? term : 0.0;    // fp32 cmp (t0 <= te) as in ref
        }
        const double td = (double)t;
        const double feat0 = a * exp(-2.0 * td);
        const double feat1 = Qs[c0] * exp(-td);

        const int cur = hss[((unsigned)(cnt - 1)) & (unsigned)(Hh - 1)];
        const double eff0 = (cur == 0) ? 1.0 : -1.0;
        const double loglam = bse + (wn0 * feat0 - wn1 * feat1) * eff0;

        contrib = isEvent ? loglam : (-RESd * exp(loglam));
    }

    // ---- block reduction + one fp64 atomic ----
    red[tid] = contrib;
    __syncthreads();
    for (int s = 128; s > 0; s >>= 1) {
        if (tid < s) red[tid] += red[tid + s];
        __syncthreads();
    }
    if (tid == 0) atomicAdd(acc, red[0]);
}

__global__ void finalize_kernel(const double* __restrict__ acc, float* __restrict__ out)
{
    out[0] = (float)acc[0];
}

extern "C" void kernel_launch(void* const* d_in, const int* in_sizes, int n_in,
                              void* d_out, int out_size, void* d_ws, size_t ws_size,
                              hipStream_t stream) {
    const float* times0      = (const float*)d_in[0];
    const int*   states0     = (const int*)  d_in[1];
    const float* times1      = (const float*)d_in[2];
    const int*   states1     = (const int*)  d_in[3];
    const float* head_times  = (const float*)d_in[4];
    const int*   head_states = (const int*)  d_in[5];
    const float* base        = (const float*)d_in[6];
    const float* weights     = (const float*)d_in[7];

    double* acc = (double*)d_ws;
    hipMemsetAsync(acc, 0, sizeof(double), stream);

    const int nblocks = Bb * GB + Bb;   // 2048 grid + 128 event blocks
    llm_kernel<<<nblocks, 256, 0, stream>>>(times0, states0, times1, states1,
                                            head_times, head_states, base, weights, acc);
    finalize_kernel<<<1, 1, 0, stream>>>(acc, (float*)d_out);
}

// Round 2
// 80.994 us; speedup vs baseline: 1.3000x; 1.3000x over previous
//
#include <hip/hip_runtime.h>
#include <math.h>

// Problem constants (from reference setup_inputs)
constexpr int Bb = 128;   // batches
constexpr int Nn = 64;    // events per sequence
constexpr int Hh = 128;   // head events
constexpr int Gg = 4000;  // grid points
constexpr float  TOLf = 0.5f;
constexpr double RESd = 0.03;

constexpr int GBLK = 8;            // grid blocks per batch (each 256 thr x 2 pts = 512 pts)
constexpr int NGRID = Bb * GBLK;   // 1024
constexpr int NBLK  = NGRID + Bb;  // + 128 event blocks = 1152
constexpr int TSTRIDE = 72;        // per-batch table stride (>=65, 16B-aligned in doubles)

// ---------------------------------------------------------------------------
// Kernel A: per-batch prefix tables. One block (64 threads = 1 wave) per batch.
//   Ps[k]  = sum_{j<k} (s1==1)? e^{t1_j} : 0
//   Qs[k]  = sum_{i<k} (s0==0)? e^{t0_i} : 0
//   W_i    = (s0==1)? e^{t0_i} : 0
//   j0_i   = #{j : t0_i - t1_j >= -TOL}   (nondecreasing in i)
//   SW[k]  = sum_{i<k} W_i
//   SWP[k] = sum_{i<k} W_i * Ps[j0_i]
//   kT[c]  = #{i : j0_i <= c},  c in [0,64]
// ---------------------------------------------------------------------------
__global__ __launch_bounds__(64) void precompute_kernel(
    const float* __restrict__ times0, const int* __restrict__ states0,
    const float* __restrict__ times1, const int* __restrict__ states1,
    double* __restrict__ Ps_all, double* __restrict__ Qs_all,
    double* __restrict__ SW_all, double* __restrict__ SWP_all,
    int* __restrict__ kT_all)
{
    const int b = blockIdx.x;
    const int i = threadIdx.x;   // 0..63

    __shared__ float  t1s[Nn];
    __shared__ int    j0s[Nn];
    __shared__ double Ps_sh[Nn + 1];

    const float t0 = times0[b * Nn + i];
    const float t1 = times1[b * Nn + i];
    const int   s0 = states0[b * Nn + i];
    const int   s1 = states1[b * Nn + i];
    t1s[i] = t1;
    __syncthreads();

    int j0 = 0;
    #pragma unroll
    for (int j = 0; j < Nn; ++j)
        j0 += (t0 - t1s[j] >= -TOLf) ? 1 : 0;   // fp32 cmp, NOT(M) prefix length
    j0s[i] = j0;

    const double e0 = exp((double)t0);
    double p = (s1 == 1) ? exp((double)t1) : 0.0;
    double q = (s0 == 0) ? e0 : 0.0;
    double W = (s0 == 1) ? e0 : 0.0;

    // inclusive wave scans (64 lanes)
    double vp = p, vq = q, vw = W;
    #pragma unroll
    for (int off = 1; off < 64; off <<= 1) {
        double op = __shfl_up(vp, off, 64);
        double oq = __shfl_up(vq, off, 64);
        double ow = __shfl_up(vw, off, 64);
        if (i >= off) { vp += op; vq += oq; vw += ow; }
    }
    Ps_sh[i + 1] = vp;
    if (i == 0) Ps_sh[0] = 0.0;
    __syncthreads();

    const double wpj = W * Ps_sh[j0];
    double vwp = wpj;
    #pragma unroll
    for (int off = 1; off < 64; off <<= 1) {
        double o = __shfl_up(vwp, off, 64);
        if (i >= off) vwp += o;
    }

    // kT[c] = #{i : j0_i <= c}
    int kc = 0;
    #pragma unroll
    for (int j = 0; j < Nn; ++j)
        kc += (j0s[j] <= i) ? 1 : 0;

    double* Ps  = Ps_all  + b * TSTRIDE;
    double* Qs  = Qs_all  + b * TSTRIDE;
    double* SW  = SW_all  + b * TSTRIDE;
    double* SWP = SWP_all + b * TSTRIDE;
    int*    kT  = kT_all  + b * TSTRIDE;

    Ps[i + 1]  = vp;  Qs[i + 1]  = vq;
    SW[i + 1]  = vw;  SWP[i + 1] = vwp;
    kT[i] = kc;
    if (i == 0) {
        Ps[0] = 0.0; Qs[0] = 0.0; SW[0] = 0.0; SWP[0] = 0.0;
        kT[Nn] = Nn;   // j0 <= 64 always
    }
}

// ---------------------------------------------------------------------------
// Kernel B: point evaluation. O(log N) per point via binary searches + tables.
//   blocks [0, NGRID): grid points, block -> (b, 512 g's), 2 pts/thread
//   blocks [NGRID, NGRID+Bb): event points, block -> b, tid in [1,128)
// ---------------------------------------------------------------------------
__global__ __launch_bounds__(256) void eval_kernel(
    const float* __restrict__ times0, const float* __restrict__ times1,
    const float* __restrict__ head_times, const int* __restrict__ head_states,
    const float* __restrict__ base, const float* __restrict__ weights,
    const double* __restrict__ Ps_all, const double* __restrict__ Qs_all,
    const double* __restrict__ SW_all, const double* __restrict__ SWP_all,
    const int* __restrict__ kT_all,
    double* __restrict__ partials)
{
    __shared__ float  t0s[Nn], t1s[Nn];
    __shared__ float  hts[Hh];
    __shared__ int    hss[Hh];
    __shared__ double Ps[Nn + 1], Qs[Nn + 1], SW[Nn + 1], SWP[Nn + 1];
    __shared__ int    kT[Nn + 1];
    __shared__ double redsh[4];

    const int tid = threadIdx.x;
    const bool isEvent = blockIdx.x >= (unsigned)NGRID;
    const int b = isEvent ? (blockIdx.x - NGRID) : (blockIdx.x / GBLK);

    if (tid < Nn) {
        t0s[tid] = times0[b * Nn + tid];
        t1s[tid] = times1[b * Nn + tid];
    } else if (tid >= 64 && tid < 64 + Nn + 1) {
        const int k = tid - 64;
        Ps[k]  = Ps_all [b * TSTRIDE + k];
        Qs[k]  = Qs_all [b * TSTRIDE + k];
        SW[k]  = SW_all [b * TSTRIDE + k];
        SWP[k] = SWP_all[b * TSTRIDE + k];
        kT[k]  = kT_all [b * TSTRIDE + k];
    }
    if (tid >= 128) {
        const int k = tid - 128;
        hts[k] = head_times[b * Hh + k];
        hss[k] = head_states[b * Hh + k];
    }
    __syncthreads();

    // softmax(weights), base — cheap per-thread
    const double w0 = (double)weights[0], w1 = (double)weights[1];
    const double mw = fmax(w0, w1);
    const double ew0 = exp(w0 - mw), ew1 = exp(w1 - mw);
    const double wn0 = ew0 / (ew0 + ew1), wn1 = ew1 / (ew0 + ew1);
    const double bse = (double)base[0];

    auto evalPoint = [&](float t, bool ev) -> double {
        const float thr = t - TOLf;               // fp32, as in reference
        // c = #{t1 < thr}
        int lo = 0, hi = Nn;
        while (lo < hi) { int m = (lo + hi) >> 1; if (t1s[m] < thr) lo = m + 1; else hi = m; }
        const int c = lo;
        // c0 = #{t0 < thr}
        lo = 0; hi = Nn;
        while (lo < hi) { int m = (lo + hi) >> 1; if (t0s[m] < thr) lo = m + 1; else hi = m; }
        const int c0 = lo;
        // c1 = #{t0 <= t}
        lo = 0; hi = Nn;
        while (lo < hi) { int m = (lo + hi) >> 1; if (t0s[m] <= t) lo = m + 1; else hi = m; }
        const int c1 = lo;
        // cnt = #{hts < t}
        lo = 0; hi = Hh;
        while (lo < hi) { int m = (lo + hi) >> 1; if (hts[m] < t) lo = m + 1; else hi = m; }
        const int cnt = lo;

        const int m = min(c1, kT[c]);
        const double Pc = Ps[c];
        const double a = Pc * SW[m] - SWP[m];     // = sum_i W_i * max(Pc - Ps[j0_i], 0)
        const double ed = exp(-(double)t);
        const double feat0 = a * ed * ed;
        const double feat1 = Qs[c0] * ed;

        const int cur = hss[((unsigned)(cnt - 1)) & (unsigned)(Hh - 1)];
        const double eff0 = (cur == 0) ? 1.0 : -1.0;
        const double loglam = bse + (wn0 * feat0 - wn1 * feat1) * eff0;
        return ev ? loglam : (-RESd * exp(loglam));
    };

    double contrib = 0.0;
    if (isEvent) {
        if (tid >= 1 && tid < Hh) contrib = evalPoint(hts[tid], true);
    } else {
        const int gbase = (blockIdx.x % GBLK) * 512;
        const int g0 = gbase + tid, g1 = gbase + tid + 256;
        if (g0 < Gg) contrib  = evalPoint((float)g0 * 0.03f, false);
        if (g1 < Gg) contrib += evalPoint((float)g1 * 0.03f, false);
    }

    // block reduction: wave shuffle, then 4-entry LDS
    double v = contrib;
    #pragma unroll
    for (int off = 32; off > 0; off >>= 1) v += __shfl_down(v, off, 64);
    if ((tid & 63) == 0) redsh[tid >> 6] = v;
    __syncthreads();
    if (tid == 0) partials[blockIdx.x] = redsh[0] + redsh[1] + redsh[2] + redsh[3];
}

// ---------------------------------------------------------------------------
// Kernel C: reduce partials -> out
// ---------------------------------------------------------------------------
__global__ __launch_bounds__(256) void finalize_kernel(
    const double* __restrict__ partials, float* __restrict__ out)
{
    __shared__ double redsh[4];
    const int tid = threadIdx.x;
    double v = 0.0;
    for (int i = tid; i < NBLK; i += 256) v += partials[i];
    #pragma unroll
    for (int off = 32; off > 0; off >>= 1) v += __shfl_down(v, off, 64);
    if ((tid & 63) == 0) redsh[tid >> 6] = v;
    __syncthreads();
    if (tid == 0) out[0] = (float)(redsh[0] + redsh[1] + redsh[2] + redsh[3]);
}

extern "C" void kernel_launch(void* const* d_in, const int* in_sizes, int n_in,
                              void* d_out, int out_size, void* d_ws, size_t ws_size,
                              hipStream_t stream) {
    const float* times0      = (const float*)d_in[0];
    const int*   states0     = (const int*)  d_in[1];
    const float* times1      = (const float*)d_in[2];
    const int*   states1     = (const int*)  d_in[3];
    const float* head_times  = (const float*)d_in[4];
    const int*   head_states = (const int*)  d_in[5];
    const float* base        = (const float*)d_in[6];
    const float* weights     = (const float*)d_in[7];

    double* Ps_all  = (double*)d_ws;
    double* Qs_all  = Ps_all  + Bb * TSTRIDE;
    double* SW_all  = Qs_all  + Bb * TSTRIDE;
    double* SWP_all = SW_all  + Bb * TSTRIDE;
    int*    kT_all  = (int*)(SWP_all + Bb * TSTRIDE);
    double* partials = (double*)(kT_all + Bb * TSTRIDE);  // 36864B offset, 8-aligned

    precompute_kernel<<<Bb, 64, 0, stream>>>(times0, states0, times1, states1,
                                             Ps_all, Qs_all, SW_all, SWP_all, kT_all);
    eval_kernel<<<NBLK, 256, 0, stream>>>(times0, times1, head_times, head_states,
                                          base, weights,
                                          Ps_all, Qs_all, SW_all, SWP_all, kT_all,
                                          partials);
    finalize_kernel<<<1, 256, 0, stream>>>(partials, (float*)d_out);
}

// Round 3
// 77.641 us; speedup vs baseline: 1.3561x; 1.0432x over previous
//
#include <hip/hip_runtime.h>
#include <math.h>

// Problem constants (from reference setup_inputs)
constexpr int Bb = 128;   // batches
constexpr int Nn = 64;    // events per sequence
constexpr int Hh = 128;   // head events
constexpr int Gg = 4000;  // grid points
constexpr float  TOLf = 0.5f;
constexpr double RESd = 0.03;

constexpr int GBLK  = 16;           // grid blocks per batch, 256 pts each (4096 >= 4000)
constexpr int NGRID = Bb * GBLK;    // 2048
constexpr int NBLK  = NGRID + Bb;   // + 128 event blocks = 2176
constexpr int TSTRIDE = 72;         // per-batch table stride in elements

// ---------------------------------------------------------------------------
// Branchless lower/upper bounds over sorted LDS arrays.
//   lb64: #{a[i] <  key}, i<64     ub64: #{a[i] <= key}, i<64
//   lb128: #{a[i] < key}, i<128
// 6 (7) predicated steps + one fixup step; all ds_read+v_cmp+cndmask.
// ---------------------------------------------------------------------------
__device__ __forceinline__ int lb64(const float* __restrict__ a, float key) {
    int lo = (a[31] < key) ? 32 : 0;
    lo += (a[lo + 15] < key) ? 16 : 0;
    lo += (a[lo + 7]  < key) ? 8  : 0;
    lo += (a[lo + 3]  < key) ? 4  : 0;
    lo += (a[lo + 1]  < key) ? 2  : 0;
    lo += (a[lo]      < key) ? 1  : 0;
    lo += (a[lo]      < key) ? 1  : 0;   // lo<=63 here; resolves count==64
    return lo;
}
__device__ __forceinline__ int ub64(const float* __restrict__ a, float key) {
    int lo = (a[31] <= key) ? 32 : 0;
    lo += (a[lo + 15] <= key) ? 16 : 0;
    lo += (a[lo + 7]  <= key) ? 8  : 0;
    lo += (a[lo + 3]  <= key) ? 4  : 0;
    lo += (a[lo + 1]  <= key) ? 2  : 0;
    lo += (a[lo]      <= key) ? 1  : 0;
    lo += (a[lo]      <= key) ? 1  : 0;
    return lo;
}
__device__ __forceinline__ int lb128(const float* __restrict__ a, float key) {
    int lo = (a[63] < key) ? 64 : 0;
    lo += (a[lo + 31] < key) ? 32 : 0;
    lo += (a[lo + 15] < key) ? 16 : 0;
    lo += (a[lo + 7]  < key) ? 8  : 0;
    lo += (a[lo + 3]  < key) ? 4  : 0;
    lo += (a[lo + 1]  < key) ? 2  : 0;
    lo += (a[lo]      < key) ? 1  : 0;
    lo += (a[lo]      < key) ? 1  : 0;   // lo<=127 here; resolves count==128
    return lo;
}

// ---------------------------------------------------------------------------
// Kernel A: per-batch prefix tables (unchanged from R2; one wave per batch).
// ---------------------------------------------------------------------------
__global__ __launch_bounds__(64) void precompute_kernel(
    const float* __restrict__ times0, const int* __restrict__ states0,
    const float* __restrict__ times1, const int* __restrict__ states1,
    double* __restrict__ Ps_all, double* __restrict__ Qs_all,
    double* __restrict__ SW_all, double* __restrict__ SWP_all,
    int* __restrict__ kT_all)
{
    const int b = blockIdx.x;
    const int i = threadIdx.x;   // 0..63

    __shared__ float  t1s[Nn];
    __shared__ int    j0s[Nn];
    __shared__ double Ps_sh[Nn + 1];

    const float t0 = times0[b * Nn + i];
    const float t1 = times1[b * Nn + i];
    const int   s0 = states0[b * Nn + i];
    const int   s1 = states1[b * Nn + i];
    t1s[i] = t1;
    __syncthreads();

    int j0 = 0;
    #pragma unroll
    for (int j = 0; j < Nn; ++j)
        j0 += (t0 - t1s[j] >= -TOLf) ? 1 : 0;   // fp32 cmp, NOT(M) prefix length
    j0s[i] = j0;

    const double e0 = exp((double)t0);
    double vp = (s1 == 1) ? exp((double)t1) : 0.0;
    double vq = (s0 == 0) ? e0 : 0.0;
    const double W = (s0 == 1) ? e0 : 0.0;
    double vw = W;

    #pragma unroll
    for (int off = 1; off < 64; off <<= 1) {
        double op = __shfl_up(vp, off, 64);
        double oq = __shfl_up(vq, off, 64);
        double ow = __shfl_up(vw, off, 64);
        if (i >= off) { vp += op; vq += oq; vw += ow; }
    }
    Ps_sh[i + 1] = vp;
    if (i == 0) Ps_sh[0] = 0.0;
    __syncthreads();

    double vwp = W * Ps_sh[j0];
    #pragma unroll
    for (int off = 1; off < 64; off <<= 1) {
        double o = __shfl_up(vwp, off, 64);
        if (i >= off) vwp += o;
    }

    int kc = 0;
    #pragma unroll
    for (int j = 0; j < Nn; ++j)
        kc += (j0s[j] <= i) ? 1 : 0;

    double* Ps  = Ps_all  + b * TSTRIDE;
    double* Qs  = Qs_all  + b * TSTRIDE;
    double* SW  = SW_all  + b * TSTRIDE;
    double* SWP = SWP_all + b * TSTRIDE;
    int*    kT  = kT_all  + b * TSTRIDE;

    Ps[i + 1]  = vp;  Qs[i + 1]  = vq;
    SW[i + 1]  = vw;  SWP[i + 1] = vwp;
    kT[i] = kc;
    if (i == 0) {
        Ps[0] = 0.0; Qs[0] = 0.0; SW[0] = 0.0; SWP[0] = 0.0;
        kT[Nn] = Nn;
    }
}

// ---------------------------------------------------------------------------
// Kernel B: point evaluation.
//   Grid blocks: per-block tables rescaled by e^{-t_base} so the per-point
//   tail runs in fp32 with native __expf (no fp64 soft-exp).
//   Event blocks: unscaled tables, fp64 tail (no final exp needed), 1 fp64
//   exp per point over only 16k points.
// ---------------------------------------------------------------------------
__global__ __launch_bounds__(256) void eval_kernel(
    const float* __restrict__ times0, const float* __restrict__ times1,
    const float* __restrict__ head_times, const int* __restrict__ head_states,
    const float* __restrict__ base, const float* __restrict__ weights,
    const double* __restrict__ Ps_all, const double* __restrict__ Qs_all,
    const double* __restrict__ SW_all, const double* __restrict__ SWP_all,
    const int* __restrict__ kT_all,
    double* __restrict__ partials)
{
    __shared__ float  t0s[Nn], t1s[Nn];
    __shared__ float  hts[Hh];
    __shared__ int    hss[Hh];
    __shared__ double Ps[Nn + 1], Qs[Nn + 1], SW[Nn + 1], SWP[Nn + 1];
    __shared__ int    kT[Nn + 1];
    __shared__ double wsh[3];     // wn0, wn1, base
    __shared__ double redsh[4];

    const int tid = threadIdx.x;
    const bool isEvent = blockIdx.x >= (unsigned)NGRID;
    const int b     = isEvent ? (blockIdx.x - NGRID) : (blockIdx.x >> 4);
    const int gbase = isEvent ? 0 : ((blockIdx.x & 15) << 8);
    const double tbase = (double)gbase * 0.03;

    if (tid < Nn) {
        t0s[tid] = times0[b * Nn + tid];
        t1s[tid] = times1[b * Nn + tid];
    } else if (tid < 192) {
        const int k = tid - 64;
        hts[k] = head_times[b * Hh + k];
        hss[k] = head_states[b * Hh + k];
    } else {
        const double sE = isEvent ? 1.0 : exp(-tbase);
        int k = tid - 192;
        const int base_i = b * TSTRIDE;
        Ps[k]  = Ps_all [base_i + k] * sE;
        Qs[k]  = Qs_all [base_i + k] * sE;
        SW[k]  = SW_all [base_i + k] * sE;
        SWP[k] = SWP_all[base_i + k] * (sE * sE);
        kT[k]  = kT_all [base_i + k];
        if (tid == 192) {          // entry 64
            k = Nn;
            Ps[k]  = Ps_all [base_i + k] * sE;
            Qs[k]  = Qs_all [base_i + k] * sE;
            SW[k]  = SW_all [base_i + k] * sE;
            SWP[k] = SWP_all[base_i + k] * (sE * sE);
            kT[k]  = kT_all [base_i + k];
        }
    }
    if (tid == 0) {
        const double w0 = (double)weights[0], w1 = (double)weights[1];
        const double mw = fmax(w0, w1);
        const double e0 = exp(w0 - mw), e1 = exp(w1 - mw);
        wsh[0] = e0 / (e0 + e1);
        wsh[1] = e1 / (e0 + e1);
        wsh[2] = (double)base[0];
    }
    __syncthreads();

    double contrib = 0.0;

    if (isEvent) {
        if (tid >= 1 && tid < Hh) {
            const float tf = hts[tid];
            const float thr = tf - TOLf;
            const int c   = lb64(t1s, thr);
            const int c0  = lb64(t0s, thr);
            const int c1  = ub64(t0s, tf);
            const int cnt = lb128(hts, tf);

            const int m = min(c1, kT[c]);
            const double a  = Ps[c] * SW[m] - SWP[m];
            const double ed = exp(-(double)tf);
            const double f0 = a * ed * ed;
            const double f1 = Qs[c0] * ed;
            const int cur = hss[((unsigned)(cnt - 1)) & (unsigned)(Hh - 1)];
            const double eff = (cur == 0) ? 1.0 : -1.0;
            contrib = wsh[2] + eff * (wsh[0] * f0 - wsh[1] * f1);
        }
    } else {
        const int g = gbase + tid;
        if (g < Gg) {
            const float tf = (float)g * 0.03f;   // matches reference fp32 grid
            const float thr = tf - TOLf;
            const int c   = lb64(t1s, thr);
            const int c0  = lb64(t0s, thr);
            const int c1  = ub64(t0s, tf);
            const int cnt = lb128(hts, tf);

            const int m = min(c1, kT[c]);
            const double a = Ps[c] * SW[m] - SWP[m];    // scaled by e^{-2 t_base}
            const double dt = (double)tf - tbase;        // in [0, ~7.68]
            const float f0 = (float)a * __expf((float)(-2.0 * dt));
            const float f1 = (float)Qs[c0] * __expf((float)(-dt));
            const int cur = hss[((unsigned)(cnt - 1)) & (unsigned)(Hh - 1)];
            const float eff = (cur == 0) ? 1.0f : -1.0f;
            const float ll = (float)wsh[2] + eff * ((float)wsh[0] * f0 - (float)wsh[1] * f1);
            contrib = -RESd * (double)__expf(ll);
        }
    }

    // block reduction: wave shuffle, then 4-entry LDS
    double v = contrib;
    #pragma unroll
    for (int off = 32; off > 0; off >>= 1) v += __shfl_down(v, off, 64);
    if ((tid & 63) == 0) redsh[tid >> 6] = v;
    __syncthreads();
    if (tid == 0) partials[blockIdx.x] = redsh[0] + redsh[1] + redsh[2] + redsh[3];
}

// ---------------------------------------------------------------------------
// Kernel C: reduce partials -> out
// ---------------------------------------------------------------------------
__global__ __launch_bounds__(256) void finalize_kernel(
    const double* __restrict__ partials, float* __restrict__ out)
{
    __shared__ double redsh[4];
    const int tid = threadIdx.x;
    double v = 0.0;
    for (int i = tid; i < NBLK; i += 256) v += partials[i];
    #pragma unroll
    for (int off = 32; off > 0; off >>= 1) v += __shfl_down(v, off, 64);
    if ((tid & 63) == 0) redsh[tid >> 6] = v;
    __syncthreads();
    if (tid == 0) out[0] = (float)(redsh[0] + redsh[1] + redsh[2] + redsh[3]);
}

extern "C" void kernel_launch(void* const* d_in, const int* in_sizes, int n_in,
                              void* d_out, int out_size, void* d_ws, size_t ws_size,
                              hipStream_t stream) {
    const float* times0      = (const float*)d_in[0];
    const int*   states0     = (const int*)  d_in[1];
    const float* times1      = (const float*)d_in[2];
    const int*   states1     = (const int*)  d_in[3];
    const float* head_times  = (const float*)d_in[4];
    const int*   head_states = (const int*)  d_in[5];
    const float* base        = (const float*)d_in[6];
    const float* weights     = (const float*)d_in[7];

    double* Ps_all  = (double*)d_ws;
    double* Qs_all  = Ps_all  + Bb * TSTRIDE;
    double* SW_all  = Qs_all  + Bb * TSTRIDE;
    double* SWP_all = SW_all  + Bb * TSTRIDE;
    int*    kT_all  = (int*)(SWP_all + Bb * TSTRIDE);
    double* partials = (double*)(kT_all + Bb * TSTRIDE);   // 8B-aligned

    precompute_kernel<<<Bb, 64, 0, stream>>>(times0, states0, times1, states1,
                                             Ps_all, Qs_all, SW_all, SWP_all, kT_all);
    eval_kernel<<<NBLK, 256, 0, stream>>>(times0, times1, head_times, head_states,
                                          base, weights,
                                          Ps_all, Qs_all, SW_all, SWP_all, kT_all,
                                          partials);
    finalize_kernel<<<1, 256, 0, stream>>>(partials, (float*)d_out);
}